// Round 12
// baseline (1054.022 us; speedup 1.0000x reference)
//
#include <hip/hip_runtime.h>
#include <stdint.h>

typedef unsigned short u16;
typedef __attribute__((ext_vector_type(8))) short short8;
typedef __attribute__((ext_vector_type(4))) float f32x4;

#define AS1 __attribute__((address_space(1)))
#define AS3 __attribute__((address_space(3)))

static __device__ __forceinline__ void gload_lds16(const void* g, void* l) {
  __builtin_amdgcn_global_load_lds((const AS1 void*)g, (AS3 void*)l, 16, 0, 0);
}

static __device__ __forceinline__ u16 bf16r(float f) {
  union { float f; uint32_t u; } c; c.f = f;
  uint32_t u = c.u;
  u += 0x7fffu + ((u >> 16) & 1u);
  return (u16)(u >> 16);
}

static constexpr int NB = 16, CIN = 256, COUT = 256, HW = 128, SDIM = 512;
static constexpr float SCALE = 1.0f / 48.0f;   // 1/sqrt(Cin*3*3)

// ---------------- K1: s[b][ci] = style[b,:] @ mod_w[ci,:] + mod_b[ci] ----------------
__global__ void k_style(const float* __restrict__ style, const float* __restrict__ mod_w,
                        const float* __restrict__ mod_b, float* __restrict__ s) {
  int b = blockIdx.x, ci = threadIdx.x;
  const float4* st = (const float4*)(style + (size_t)b * SDIM);
  const float4* mw = (const float4*)(mod_w + (size_t)ci * SDIM);
  float acc = 0.f;
  #pragma unroll 4
  for (int j = 0; j < SDIM / 4; ++j) {
    float4 a = st[j], w = mw[j];
    acc += a.x * w.x + a.y * w.y + a.z * w.z + a.w * w.w;
  }
  s[b * CIN + ci] = acc + mod_b[ci];
}

// ------- K2: modulated+demodulated weights -> bf16, packed in MFMA-fragment order ----
// Apack[b]: frag(KT, KK, wr, mt) = 512 u16 block; within block lane*8+e,
// lane = (co&15) | (((ci>>3)&3)<<4), e = ci&7.
__global__ void k_wmod(const float* __restrict__ weight, const float* __restrict__ s,
                       u16* __restrict__ Wb) {
  __shared__ float wld[CIN * 9];
  __shared__ float red[8];
  int bid = blockIdx.x;
  int b = bid >> 8, co = bid & 255;
  int t = threadIdx.x;
  const float* wsrc = weight + (size_t)co * (CIN * 9);
  for (int i = t; i < CIN * 9; i += 256) wld[i] = wsrc[i];
  __syncthreads();
  int ci = t;
  float sv = s[b * CIN + ci];
  float v[9];
  float sq = 0.f;
  #pragma unroll
  for (int k = 0; k < 9; ++k) {
    float w = SCALE * wld[ci * 9 + k] * sv;
    v[k] = w;
    sq += w * w;
  }
  #pragma unroll
  for (int off = 32; off; off >>= 1) sq += __shfl_down(sq, off);
  int lane = t & 63, wid = t >> 6;
  if (lane == 0) red[wid] = sq;
  __syncthreads();
  if (t == 0) red[4] = rsqrtf(red[0] + red[1] + red[2] + red[3] + 1e-8f);
  __syncthreads();
  float demod = red[4];
  int KK = (ci >> 5) & 1, seg = (ci >> 3) & 3, e = ci & 7;
  int lane2 = (co & 15) | (seg << 4);
  int wr = co >> 7, mt = (co >> 4) & 7;
  #pragma unroll
  for (int k = 0; k < 9; ++k) {
    int KT = k * 4 + (ci >> 6);
    size_t dst = (size_t)b * 9 * 65536 +
                 ((((size_t)KT * 2 + KK) * 2 + wr) * 8 + mt) * 512 + lane2 * 8 + e;
    Wb[dst] = bf16r(v[k] * demod);
  }
}

// ---------------- K3: x fp32 [b][ci][h][w] -> bf16 transposed padded -----------------
// xTp[b][hh][pxp][ci]: hh in [0,130) = image row h+1 (hh=0/129 zero guard rows);
// pxp in [0,130): pxp==0/129 zero pad columns, pxp=1+w.
__global__ void k_xt(const float* __restrict__ x, u16* __restrict__ xTp) {
  __shared__ u16 T[128 * 65];
  int bid = blockIdx.x;
  int b = bid >> 7, h = bid & 127;
  int t = threadIdx.x;
  size_t rowbase = ((size_t)b * 130 + (h + 1)) * 130 * CIN;
  xTp[rowbase + t] = 0;
  xTp[rowbase + (size_t)129 * CIN + t] = 0;
  if (h == 0) {
    uint32_t* g = (uint32_t*)(xTp + (size_t)b * 130 * 130 * CIN);
    for (int i = t; i < 130 * CIN / 2; i += 256) g[i] = 0;
  }
  if (h == 127) {
    uint32_t* g = (uint32_t*)(xTp + ((size_t)b * 130 + 129) * 130 * CIN);
    for (int i = t; i < 130 * CIN / 2; i += 256) g[i] = 0;
  }
  int c8 = t & 7, pxb = t >> 3;
  for (int ci0 = 0; ci0 < CIN; ci0 += 64) {
    __syncthreads();
    #pragma unroll
    for (int i = 0; i < 8; ++i) {
      int idx = t + i * 256;
      int ci = idx >> 5, px4 = idx & 31;
      float4 v = *(const float4*)(x + (((size_t)b * CIN + ci0 + ci) * HW + h) * HW + px4 * 4);
      T[(px4 * 4 + 0) * 65 + ci] = bf16r(v.x);
      T[(px4 * 4 + 1) * 65 + ci] = bf16r(v.y);
      T[(px4 * 4 + 2) * 65 + ci] = bf16r(v.z);
      T[(px4 * 4 + 3) * 65 + ci] = bf16r(v.w);
    }
    __syncthreads();
    #pragma unroll
    for (int i = 0; i < 4; ++i) {
      int px = i * 32 + pxb;
      short8 v;
      #pragma unroll
      for (int j = 0; j < 8; ++j) v[j] = (short)T[px * 65 + c8 * 8 + j];
      *(short8*)&xTp[rowbase + (size_t)(px + 1) * CIN + ci0 + c8 * 8] = v;
    }
  }
}

// ------ K4: implicit GEMM conv: A direct (fragment-packed, coalesced), B via LDS ----
// block = (b, hp): out 256co x 256px (rows 2hp,2hp+1). 8 waves 2Mx4N, wave 128x64.
// K = 36 K-tiles of 64 (2 kk-halves). A frags load straight from packed Wb (1KB
// contiguous per instr, L1/L2-served), 3-array ping-pong rolling window. B staged via
// gload_lds (swizzled, dbuf 2x32KB), raw barrier + counted vmcnt per kt.
// NOTE __launch_bounds__(512,1): 2nd arg is min waves/SIMD; (512,2) caps VGPR at 128
// and spills the ~230-reg working set (R9 failure: WRITE_SIZE 262MB -> 1.62GB).
static constexpr int BSLOT = 16384;  // u16 per B slot (256 rows x 64)

__global__ __launch_bounds__(512, 1) void k_conv(const u16* __restrict__ Wb,
                                                 const u16* __restrict__ xTp,
                                                 const float* __restrict__ bias,
                                                 float* __restrict__ out) {
  extern __shared__ u16 lds[];
  int bid = blockIdx.x;
  // T1: bijective XCD swizzle (nwg=1024, 1024%8==0); 2 b-values/XCD -> Wb L2-resident
  int swz = (bid & 7) * 128 + (bid >> 3);
  int b = swz >> 6, hp = swz & 63;
  int h0 = hp * 2;

  int t = threadIdx.x, lane = t & 63, wid = t >> 6;
  int wr = wid >> 2, wc = wid & 3;
  int rowoff = wid * 8 + (lane >> 3);               // staging row within 64-row unit
  int swzc = ((lane & 7) ^ (lane >> 3)) << 3;       // pre-swizzled source col (u16)
  int cxor = (lane & 7) << 3;                       // read-side XOR
  int klo = (lane >> 4) << 3;
  int bro = (wc * 64 + (lane & 15)) * 64;           // + nt*1024
  const u16* Ab = Wb + (size_t)b * 9 * 65536;
  const size_t xB = (size_t)b * 130 * 130 * 256;

  f32x4 acc[8][4];
  #pragma unroll
  for (int i = 0; i < 8; ++i)
    #pragma unroll
    for (int j = 0; j < 4; ++j) acc[i][j] = (f32x4)0.f;

#define LOADA(DST, KT, KK)                                                       \
  do {                                                                           \
    const u16* p_ = Ab + (size_t)((((KT) * 2 + (KK)) * 2 + wr) * 8) * 512        \
                    + lane * 8;                                                  \
    _Pragma("unroll")                                                            \
    for (int mt = 0; mt < 8; ++mt) DST[mt] = *(const short8*)(p_ + mt * 512);    \
  } while (0)

#define STAGEB(KT)                                                               \
  do {                                                                           \
    int kpos_ = (KT) >> 2, ci0_ = ((KT) & 3) << 6;                               \
    int kh_ = kpos_ < 3 ? 0 : (kpos_ < 6 ? 1 : 2);                               \
    int kw_ = kpos_ - kh_ * 3;                                                   \
    u16* d_ = lds + ((KT) & 1) * BSLOT;                                          \
    _Pragma("unroll")                                                            \
    for (int i = 0; i < 4; ++i) {                                                \
      int hh_ = h0 + kh_ + (i >> 1);                                             \
      int pxp_ = kw_ + (i & 1) * 64 + rowoff;                                    \
      const u16* s_ = xTp + xB + ((size_t)hh_ * 130 + pxp_) * 256 + ci0_ + swzc; \
      gload_lds16(s_, d_ + (i * 64 + wid * 8) * 64);                             \
    }                                                                            \
  } while (0)

#define LD4B(S, KK)                                                              \
  do {                                                                           \
    _Pragma("unroll")                                                            \
    for (int nt = 0; nt < 4; ++nt)                                               \
      bf[nt] = *(const short8*)&(S)[bro + nt * 1024 + ((((KK) * 32) + klo) ^ cxor)]; \
  } while (0)

#define MFMA32(AF)                                                               \
  _Pragma("unroll")                                                              \
  for (int mt = 0; mt < 8; ++mt)                                                 \
    _Pragma("unroll")                                                            \
    for (int nt = 0; nt < 4; ++nt)                                               \
      acc[mt][nt] =                                                              \
          __builtin_amdgcn_mfma_f32_16x16x32_bf16(AF[mt], bf[nt], acc[mt][nt], 0, 0, 0);

#define KTBODY(KT, AC, AN)                                                       \
  {                                                                              \
    const u16* S_ = lds + ((KT) & 1) * BSLOT;                                    \
    bool pf_ = (KT) + 1 < 36;                                                    \
    if (pf_) STAGEB((KT) + 1);                                                   \
    LOADA(aZ, (KT), 1);                                                          \
    LD4B(S_, 0);                                                                 \
    __builtin_amdgcn_s_setprio(1);                                               \
    MFMA32(AC);                                                                  \
    __builtin_amdgcn_s_setprio(0);                                               \
    if (pf_) LOADA(AN, (KT) + 1, 0);                                             \
    LD4B(S_, 1);                                                                 \
    __builtin_amdgcn_s_setprio(1);                                               \
    MFMA32(aZ);                                                                  \
    __builtin_amdgcn_s_setprio(0);                                               \
    asm volatile("" ::: "memory");                                               \
    __builtin_amdgcn_s_barrier();                                                \
    asm volatile("" ::: "memory");                                               \
  }

  short8 aX[8], aY[8], aZ[8], bf[4];
  // prologue: stage B tile0; load A(0,kk0); prove stages landed (8 A-loads younger)
  STAGEB(0);
  LOADA(aX, 0, 0);
  asm volatile("s_waitcnt vmcnt(8)" ::: "memory");
  __builtin_amdgcn_s_barrier();
  asm volatile("" ::: "memory");

  #pragma unroll 1
  for (int kt = 0; kt < 36; kt += 2) {
    KTBODY(kt, aX, aY);
    KTBODY(kt + 1, aY, aX);
  }
#undef LOADA
#undef STAGEB
#undef LD4B
#undef MFMA32
#undef KTBODY

  // -------- epilogue: C write --------
  #pragma unroll
  for (int mt = 0; mt < 8; ++mt) {
    #pragma unroll
    for (int j = 0; j < 4; ++j) {
      int co = wr * 128 + mt * 16 + ((lane >> 4) * 4) + j;
      float bv = bias[co];
      #pragma unroll
      for (int nt = 0; nt < 4; ++nt) {
        int px = wc * 64 + nt * 16 + (lane & 15);
        int h = h0 + (px >> 7), w = px & 127;
        out[(((size_t)b * COUT + co) * HW + h) * HW + w] = acc[mt][nt][j] + bv;
      }
    }
  }
}

extern "C" void kernel_launch(void* const* d_in, const int* in_sizes, int n_in,
                              void* d_out, int out_size, void* d_ws, size_t ws_size,
                              hipStream_t stream) {
  const float* x      = (const float*)d_in[0];
  const float* style  = (const float*)d_in[1];
  const float* weight = (const float*)d_in[2];
  const float* mod_w  = (const float*)d_in[3];
  const float* mod_b  = (const float*)d_in[4];
  const float* bias   = (const float*)d_in[5];
  float* out = (float*)d_out;

  char* ws = (char*)d_ws;
  float* s   = (float*)ws;                                           // 16 KB
  u16* Wb    = (u16*)(ws + 16384);                                   // 18.9 MB (packed)
  u16* xTp   = (u16*)(ws + 16384 + (size_t)NB * 9 * COUT * CIN * 2); // 138.4 MB

  (void)hipFuncSetAttribute((const void*)k_conv,
                            hipFuncAttributeMaxDynamicSharedMemorySize, 2 * BSLOT * 2);

  k_style<<<NB, 256, 0, stream>>>(style, mod_w, mod_b, s);
  k_wmod<<<NB * COUT, 256, 0, stream>>>(weight, s, Wb);
  k_xt<<<NB * HW, 256, 0, stream>>>(x, xTp);
  k_conv<<<NB * (HW / 2), 512, 2 * BSLOT * 2, stream>>>(Wb, xTp, bias, out);
}

// Round 13
// 435.683 us; speedup vs baseline: 2.4192x; 2.4192x over previous
//
#include <hip/hip_runtime.h>
#include <stdint.h>

typedef unsigned short u16;
typedef __attribute__((ext_vector_type(8))) short short8;
typedef __attribute__((ext_vector_type(16))) float f32x16;

#define AS1 __attribute__((address_space(1)))
#define AS3 __attribute__((address_space(3)))

static __device__ __forceinline__ void gload_lds16(const void* g, void* l) {
  __builtin_amdgcn_global_load_lds((const AS1 void*)g, (AS3 void*)l, 16, 0, 0);
}

static __device__ __forceinline__ u16 bf16r(float f) {
  union { float f; uint32_t u; } c; c.f = f;
  uint32_t u = c.u;
  u += 0x7fffu + ((u >> 16) & 1u);
  return (u16)(u >> 16);
}

static constexpr int NB = 16, CIN = 256, COUT = 256, HW = 128, SDIM = 512;
static constexpr float SCALE = 1.0f / 48.0f;   // 1/sqrt(Cin*3*3)

// ---------------- K1: s[b][ci] = style[b,:] @ mod_w[ci,:] + mod_b[ci] ----------------
__global__ void k_style(const float* __restrict__ style, const float* __restrict__ mod_w,
                        const float* __restrict__ mod_b, float* __restrict__ s) {
  int b = blockIdx.x, ci = threadIdx.x;
  const float4* st = (const float4*)(style + (size_t)b * SDIM);
  const float4* mw = (const float4*)(mod_w + (size_t)ci * SDIM);
  float acc = 0.f;
  #pragma unroll 4
  for (int j = 0; j < SDIM / 4; ++j) {
    float4 a = st[j], w = mw[j];
    acc += a.x * w.x + a.y * w.y + a.z * w.z + a.w * w.w;
  }
  s[b * CIN + ci] = acc + mod_b[ci];
}

// ---------------- K2: modulated+demodulated weights -> bf16 Wb[b][kpos][co][ci] ------
__global__ void k_wmod(const float* __restrict__ weight, const float* __restrict__ s,
                       u16* __restrict__ Wb) {
  __shared__ float wld[CIN * 9];
  __shared__ float red[8];
  int bid = blockIdx.x;
  int b = bid >> 8, co = bid & 255;
  int t = threadIdx.x;
  const float* wsrc = weight + (size_t)co * (CIN * 9);
  for (int i = t; i < CIN * 9; i += 256) wld[i] = wsrc[i];
  __syncthreads();
  int ci = t;
  float sv = s[b * CIN + ci];
  float v[9];
  float sq = 0.f;
  #pragma unroll
  for (int k = 0; k < 9; ++k) {
    float w = SCALE * wld[ci * 9 + k] * sv;
    v[k] = w;
    sq += w * w;
  }
  #pragma unroll
  for (int off = 32; off; off >>= 1) sq += __shfl_down(sq, off);
  int lane = t & 63, wid = t >> 6;
  if (lane == 0) red[wid] = sq;
  __syncthreads();
  if (t == 0) red[4] = rsqrtf(red[0] + red[1] + red[2] + red[3] + 1e-8f);
  __syncthreads();
  float demod = red[4];
  #pragma unroll
  for (int k = 0; k < 9; ++k) {
    Wb[(((size_t)b * 9 + k) * COUT + co) * CIN + ci] = bf16r(v[k] * demod);
  }
}

// ---------------- K3: x fp32 [b][ci][h][w] -> bf16 transposed padded -----------------
// xTp[b][hh][pxp][ci]: hh in [0,130) = image row h+1 (hh=0/129 zero guard rows);
// pxp in [0,130): pxp==0/129 zero pad columns, pxp=1+w.
__global__ void k_xt(const float* __restrict__ x, u16* __restrict__ xTp) {
  __shared__ u16 T[128 * 65];
  int bid = blockIdx.x;
  int b = bid >> 7, h = bid & 127;
  int t = threadIdx.x;
  size_t rowbase = ((size_t)b * 130 + (h + 1)) * 130 * CIN;
  xTp[rowbase + t] = 0;
  xTp[rowbase + (size_t)129 * CIN + t] = 0;
  if (h == 0) {
    uint32_t* g = (uint32_t*)(xTp + (size_t)b * 130 * 130 * CIN);
    for (int i = t; i < 130 * CIN / 2; i += 256) g[i] = 0;
  }
  if (h == 127) {
    uint32_t* g = (uint32_t*)(xTp + ((size_t)b * 130 + 129) * 130 * CIN);
    for (int i = t; i < 130 * CIN / 2; i += 256) g[i] = 0;
  }
  int c8 = t & 7, pxb = t >> 3;
  for (int ci0 = 0; ci0 < CIN; ci0 += 64) {
    __syncthreads();
    #pragma unroll
    for (int i = 0; i < 8; ++i) {
      int idx = t + i * 256;
      int ci = idx >> 5, px4 = idx & 31;
      float4 v = *(const float4*)(x + (((size_t)b * CIN + ci0 + ci) * HW + h) * HW + px4 * 4);
      T[(px4 * 4 + 0) * 65 + ci] = bf16r(v.x);
      T[(px4 * 4 + 1) * 65 + ci] = bf16r(v.y);
      T[(px4 * 4 + 2) * 65 + ci] = bf16r(v.z);
      T[(px4 * 4 + 3) * 65 + ci] = bf16r(v.w);
    }
    __syncthreads();
    #pragma unroll
    for (int i = 0; i < 4; ++i) {
      int px = i * 32 + pxb;
      short8 v;
      #pragma unroll
      for (int j = 0; j < 8; ++j) v[j] = (short)T[px * 65 + c8 * 8 + j];
      *(short8*)&xTp[rowbase + (size_t)(px + 1) * CIN + ci0 + c8 * 8] = v;
    }
  }
}

// ------- K4: implicit GEMM conv, R5 structure + 32x32x16 MFMA (higher MFMA ceiling) --
// block = (b, hp): out tile 256co x 256px (rows 2hp,2hp+1). 8 waves 2Mx4N, wave
// 128x64 built from 32x32 frags (mt 0..3, nt 0..1). K = 36 K-tiles of 64 = 4 ksteps
// of 16. LDS 2 slots x (A 32KB + B 32KB), R5 layout + XOR swizzle verbatim
// (read pattern per 16-lane group identical to R5's measured-0-conflict pattern).
// ONE __syncthreads per kt (R5's best-measured schedule).
static constexpr int SLOTU = 32768;  // u16 per slot

__global__ __launch_bounds__(512, 2) void k_conv(const u16* __restrict__ Wb,
                                                 const u16* __restrict__ xTp,
                                                 const float* __restrict__ bias,
                                                 float* __restrict__ out) {
  extern __shared__ u16 lds[];
  int bid = blockIdx.x;
  // T1: bijective XCD swizzle (nwg=1024, 1024%8==0)
  int swz = (bid & 7) * 128 + (bid >> 3);
  int b = swz >> 6, hp = swz & 63;
  int h0 = hp * 2;

  int t = threadIdx.x, lane = t & 63, wid = t >> 6;
  int wr = wid >> 2, wc = wid & 3;
  int l31 = lane & 31, seg = lane >> 5, c7 = l31 & 7;
  int rowoff = wid * 8 + (lane >> 3);               // staging row within 64-row unit
  int swzc = ((lane & 7) ^ (lane >> 3)) << 3;       // pre-swizzled source col (u16)
  int aro = (wr * 128 + l31) * 64;                  // + mt*2048
  int bro = 16384 + (wc * 64 + l31) * 64;           // + nt*2048
  const size_t wbB = (size_t)b * 9 * 65536;
  const size_t xB = (size_t)b * 130 * 130 * 256;

  f32x16 acc[4][2];
  #pragma unroll
  for (int i = 0; i < 4; ++i)
    #pragma unroll
    for (int j = 0; j < 2; ++j) acc[i][j] = (f32x16)0.f;

  auto srcA = [&](int kta, int i) -> const u16* {
    int kpos = kta >> 2, ci0 = (kta & 3) << 6;
    return Wb + wbB + (size_t)kpos * 65536 + (size_t)(i * 64 + rowoff) * 256 + ci0 + swzc;
  };
  auto srcB = [&](int kta, int i) -> const u16* {
    int kpos = kta >> 2, ci0 = (kta & 3) << 6;
    int kh = kpos < 3 ? 0 : (kpos < 6 ? 1 : 2);
    int kw = kpos - kh * 3;
    int hh = h0 + kh + (i >> 1);                    // guard layout: image row = hh-1
    int pxp = kw + (i & 1) * 64 + rowoff;
    return xTp + xB + ((size_t)hh * 130 + pxp) * 256 + ci0 + swzc;
  };

  // prologue: stage kt=0 into slot 0
  {
    u16* A2 = lds;
    u16* B2 = lds + 16384;
    #pragma unroll
    for (int i = 0; i < 4; ++i) gload_lds16(srcA(0, i), A2 + (i * 64 + wid * 8) * 64);
    #pragma unroll
    for (int i = 0; i < 4; ++i) gload_lds16(srcB(0, i), B2 + (i * 64 + wid * 8) * 64);
  }
  __syncthreads();   // drains vmcnt + publishes slot 0

  #pragma unroll 1
  for (int kt = 0; kt < 36; ++kt) {
    const u16* Ac = lds + (kt & 1) * SLOTU;
    u16* An = lds + ((kt & 1) ^ 1) * SLOTU;
    u16* Bn = An + 16384;
    bool pf = kt < 35;
    int kta = kt + 1;

    // col unit for kstep KS: logical unit = KS*2+seg, phys = ^ (row&7) = ^ c7
#define CCOL(KS) ((((KS) * 2 + seg) ^ c7) << 3)
#define LD_A(DST, KS)                                                            \
    do {                                                                         \
      _Pragma("unroll")                                                          \
      for (int mt = 0; mt < 4; ++mt)                                             \
        DST[mt] = *(const short8*)&Ac[aro + mt * 2048 + CCOL(KS)];               \
    } while (0)
#define LD_B(DST, KS)                                                            \
    do {                                                                         \
      _Pragma("unroll")                                                          \
      for (int nt = 0; nt < 2; ++nt)                                             \
        DST[nt] = *(const short8*)&Ac[bro + nt * 2048 + CCOL(KS)];               \
    } while (0)
#define MFMA8(SA, SB)                                                            \
    _Pragma("unroll")                                                            \
    for (int mt = 0; mt < 4; ++mt) {                                             \
      acc[mt][0] = __builtin_amdgcn_mfma_f32_32x32x16_bf16(SA[mt], SB[0],        \
                                                           acc[mt][0], 0, 0, 0); \
      acc[mt][1] = __builtin_amdgcn_mfma_f32_32x32x16_bf16(SA[mt], SB[1],        \
                                                           acc[mt][1], 0, 0, 0); \
    }

    short8 sA0[4], sA1[4], sA2[4], sA3[4], sB0[2], sB1[2], sB2[2], sB3[2];
    // ks0/ks1 fragments
    LD_A(sA0, 0); LD_A(sA1, 1);
    LD_B(sB0, 0);
    // stage next A while frags are in flight
    if (pf) {
      #pragma unroll
      for (int i = 0; i < 4; ++i) gload_lds16(srcA(kta, i), An + (i * 64 + wid * 8) * 64);
    }
    LD_B(sB1, 1);
    // MFMA clusters ks0, ks1 (8 independent each; ks-chains 8 apart)
    MFMA8(sA0, sB0);
    MFMA8(sA1, sB1);
    // stage next B
    if (pf) {
      #pragma unroll
      for (int i = 0; i < 4; ++i) gload_lds16(srcB(kta, i), Bn + (i * 64 + wid * 8) * 64);
    }
    // ks2/ks3 fragments
    LD_A(sA2, 2); LD_A(sA3, 3);
    LD_B(sB2, 2); LD_B(sB3, 3);
    MFMA8(sA2, sB2);
    MFMA8(sA3, sB3);
    // boundary: __syncthreads waits vmcnt(0)+lgkmcnt(0) then barriers -> slot swap
    __syncthreads();
#undef CCOL
#undef LD_A
#undef LD_B
#undef MFMA8
  }

  // -------- epilogue: C write (32x32 layout: col=lane&31, row=(j&3)+8*(j>>2)+4*seg) --
  #pragma unroll
  for (int mt = 0; mt < 4; ++mt) {
    #pragma unroll
    for (int nt = 0; nt < 2; ++nt) {
      int px = wc * 64 + nt * 32 + l31;
      int h = h0 + (px >> 7), w = px & 127;
      #pragma unroll
      for (int j = 0; j < 16; ++j) {
        int co = wr * 128 + mt * 32 + (j & 3) + 8 * (j >> 2) + 4 * seg;
        out[(((size_t)b * COUT + co) * HW + h) * HW + w] = acc[mt][nt][j] + bias[co];
      }
    }
  }
}

extern "C" void kernel_launch(void* const* d_in, const int* in_sizes, int n_in,
                              void* d_out, int out_size, void* d_ws, size_t ws_size,
                              hipStream_t stream) {
  const float* x      = (const float*)d_in[0];
  const float* style  = (const float*)d_in[1];
  const float* weight = (const float*)d_in[2];
  const float* mod_w  = (const float*)d_in[3];
  const float* mod_b  = (const float*)d_in[4];
  const float* bias   = (const float*)d_in[5];
  float* out = (float*)d_out;

  char* ws = (char*)d_ws;
  float* s   = (float*)ws;                                           // 16 KB
  u16* Wb    = (u16*)(ws + 16384);                                   // 18.9 MB
  u16* xTp   = (u16*)(ws + 16384 + (size_t)NB * 9 * COUT * CIN * 2); // 138.4 MB

  (void)hipFuncSetAttribute((const void*)k_conv,
                            hipFuncAttributeMaxDynamicSharedMemorySize, 2 * SLOTU * 2);

  k_style<<<NB, 256, 0, stream>>>(style, mod_w, mod_b, s);
  k_wmod<<<NB * COUT, 256, 0, stream>>>(weight, s, Wb);
  k_xt<<<NB * HW, 256, 0, stream>>>(x, xTp);
  k_conv<<<NB * (HW / 2), 512, 2 * SLOTU * 2, stream>>>(Wb, xTp, bias, out);
}